// Round 7
// baseline (266.487 us; speedup 1.0000x reference)
//
#include <hip/hip_runtime.h>
#include <math.h>

#define PROW 40    // P row: [0..5]=dts, [8..23]=B, [24..39]=C

__device__ __forceinline__ float siluf_(float x) {
    return x / (1.f + __expf(-x));
}

// Direction permutation (involution): xs[k][d][l] = x0[d][sperm(k,l)]
__device__ __forceinline__ int sperm(int k, int l) {
    int t = (k & 1) ? (((l & 7) << 3) | (l >> 3)) : l;
    return (k & 2) ? (63 - t) : t;
}

// bf16 pack/unpack (RNE)
__device__ __forceinline__ unsigned int f2bf(float f) {
    unsigned int u = __float_as_uint(f);
    return (u + 0x7FFFu + ((u >> 16) & 1u)) >> 16;
}
__device__ __forceinline__ float bf2f(unsigned int h) {
    return __uint_as_float(h << 16);
}
__device__ __forceinline__ unsigned int packbf(float lo, float hi) {
    return f2bf(lo) | (f2bf(hi) << 16);
}

// ---------------------------------------------------------------- k1a: stats
__global__ void k1a_stats(const float* __restrict__ x, float* __restrict__ stats) {
    int bc = blockIdx.x;                 // b*96 + c
    const float* xp = x + (size_t)bc * 4096;
    float s = 0.f, sq = 0.f;
    for (int i = threadIdx.x; i < 4096; i += 256) {
        float v = xp[i]; s += v; sq += v * v;
    }
    __shared__ float rs[256], rq[256];
    rs[threadIdx.x] = s; rq[threadIdx.x] = sq;
    __syncthreads();
    for (int off = 128; off > 0; off >>= 1) {
        if (threadIdx.x < off) {
            rs[threadIdx.x] += rs[threadIdx.x + off];
            rq[threadIdx.x] += rq[threadIdx.x + off];
        }
        __syncthreads();
    }
    if (threadIdx.x == 0) {
        float m = rs[0] * (1.f / 4096.f);
        float v = rq[0] * (1.f / 4096.f) - m * m;
        stats[bc] = m;
        stats[384 + bc] = rsqrtf(v + 1e-5f);
    }
}

// ---- kA: spatial-norm+SiLU + LN(96) + in_proj cols [cg*96, cg*96+96)
// grid 1024, XCD-swizzled: chunk = (blk&7)*32 + ((blk>>3)>>2), cg = (blk>>3)&3
__global__ __launch_bounds__(256) void kA(
        const float* __restrict__ x, const float* __restrict__ stats,
        const float* __restrict__ gamma, const float* __restrict__ beta,
        const float* __restrict__ ln1_g, const float* __restrict__ ln1_b,
        const float* __restrict__ Win,       // (96,384)
        float* __restrict__ xcg_all,         // [chunk][192][64] f32
        unsigned int* __restrict__ zg_b) {   // [chunk][96][64] packed bf16x2
    int blk = blockIdx.x;
    int xcd = blk & 7, j = blk >> 3;
    int chunk = xcd * 32 + (j >> 2), cg = j & 3;
    int b = chunk >> 6, chh = (chunk >> 3) & 7, chw = chunk & 7;
    __shared__ float hs[64 * 97];
    int t = threadIdx.x;
    for (int i = t; i < 6144; i += 256) {
        int c = i >> 6, pos = i & 63;
        int bc = b * 96 + c;
        int hh = chh * 8 + (pos >> 3), ww = chw * 8 + (pos & 7);
        float v = x[(((size_t)bc) * 64 + hh) * 64 + ww];
        float xn = (v - stats[bc]) * stats[384 + bc] * gamma[c] + beta[c];
        hs[pos * 97 + c] = siluf_(xn);
    }
    __syncthreads();
    {   // LN over 96: 4 lanes per position
        int p = t >> 2, o = t & 3;
        float s = 0.f, sq = 0.f;
        #pragma unroll
        for (int jj = 0; jj < 24; jj++) { float v = hs[p * 97 + o + 4 * jj]; s += v; sq += v * v; }
        s += __shfl_xor(s, 1); sq += __shfl_xor(sq, 1);
        s += __shfl_xor(s, 2); sq += __shfl_xor(sq, 2);
        float m = s * (1.f / 96.f);
        float rinv = rsqrtf(sq * (1.f / 96.f) - m * m + 1e-5f);
        #pragma unroll
        for (int jj = 0; jj < 24; jj++) {
            int c = o + 4 * jj;
            hs[p * 97 + c] = (hs[p * 97 + c] - m) * rinv * ln1_g[c] + ln1_b[c];
        }
    }
    __syncthreads();
    int p = t & 63;
    int wv = __builtin_amdgcn_readfirstlane(t >> 6);   // 0..3
    int jbase = cg * 96 + wv * 24;
    float acc[24];
    #pragma unroll
    for (int i = 0; i < 24; i++) acc[i] = 0.f;
    for (int c = 0; c < 96; c++) {
        float u = hs[p * 97 + c];
        const float* w = Win + c * 384 + jbase;        // wave-uniform -> s_load
        #pragma unroll
        for (int i = 0; i < 24; i++) acc[i] = fmaf(u, w[i], acc[i]);
    }
    if (jbase < 192) {
        float* o_ = xcg_all + (size_t)chunk * 12288 + jbase * 64 + p;
        #pragma unroll
        for (int i = 0; i < 24; i++) o_[i * 64] = acc[i];
    } else {
        int i2base = (jbase - 192) >> 1;
        unsigned int* o_ = zg_b + (size_t)chunk * 6144 + i2base * 64 + p;
        #pragma unroll
        for (int i = 0; i < 12; i++) o_[i * 64] = packbf(acc[2 * i], acc[2 * i + 1]);
    }
}

// ---- kB: depthwise 3x3 + bias + SiLU; channels [dg*48, +48) -> x0T[l][192]
__global__ __launch_bounds__(256) void kB(
        const float* __restrict__ xcg_all, const float* __restrict__ conv_w,
        const float* __restrict__ conv_b, float* __restrict__ x0T_all) {
    int blk = blockIdx.x;
    int xcd = blk & 7, j = blk >> 3;
    int chunk = xcd * 32 + (j >> 2), dg = j & 3;
    int dbase = dg * 48;
    __shared__ float tile[48 * 65];
    int t = threadIdx.x;
    const float* in = xcg_all + (size_t)chunk * 12288 + dbase * 64;
    for (int i = t; i < 3072; i += 256) tile[(i >> 6) * 65 + (i & 63)] = in[i];
    __syncthreads();
    float* o = x0T_all + (size_t)chunk * 12288;
    for (int s = 0; s < 12; s++) {
        int idx = s * 256 + t;                 // < 3072
        int l = idx / 48, dl = idx - l * 48;
        int r = l >> 3, cc = l & 7;
        int d = dbase + dl;
        float acc = conv_b[d];
        #pragma unroll
        for (int dh = 0; dh < 3; dh++) {
            int rr = r + dh - 1;
            if (rr < 0 || rr > 7) continue;
            #pragma unroll
            for (int dw = 0; dw < 3; dw++) {
                int cw = cc + dw - 1;
                if (cw < 0 || cw > 7) continue;
                acc = fmaf(tile[dl * 65 + rr * 8 + cw], conv_w[d * 9 + dh * 3 + dw], acc);
            }
        }
        o[l * 192 + d] = siluf_(acc);
    }
}

// ---- kD: block = (chunk, pair). 384 thr = 2 wave-uniform k-groups (k=2p+g).
// Per group: x_proj GEMV -> pT -> Pg; scan with s_load rows; merge in LDS yac.
// pair0 writes f32 y; pair1 writes packed bf16 y.
__global__ __launch_bounds__(384, 3) void kD(
        const float* __restrict__ x0T_all, const float* __restrict__ xpw, // (4,38,192)
        const float* __restrict__ dtw, const float* __restrict__ dtb,
        const float* __restrict__ A_logs, const float* __restrict__ Ds,
        float* __restrict__ Pg_all,          // [(chunk*4+k)][64][40]
        float* __restrict__ yp0_all,         // [chunk][64][192] f32
        unsigned int* __restrict__ yp1_b) {  // [chunk][6144] packed bf16x2
    int blk = blockIdx.x;
    int xcd = blk & 7, j = blk >> 3;         // j: 0..63
    int chunk = xcd * 32 + (j >> 1);
    int pair = j & 1;
    __shared__ float yac[64 * 192];
    __shared__ float pT[2][64 * 41];
    int t = threadIdx.x;
    const float* xbase = x0T_all + (size_t)chunk * 12288;
    int g = __builtin_amdgcn_readfirstlane(t / 192);   // 0/1, wave-uniform
    int tk = t - g * 192;
    int k = pair * 2 + g;

    // init yac with the pair's D-sum term (yac[i], i = pos*192 + d)
    for (int i = t; i < 12288; i += 384) {
        int d = i % 192;
        float dsum = Ds[pair * 384 + d] + Ds[pair * 384 + 192 + d];
        yac[i] = dsum * xbase[i];
    }

    // proj: P[c][l] for this group's k
    {
        int l = tk & 63;
        int wv3 = __builtin_amdgcn_readfirstlane(tk >> 6);  // 0..2
        int cbase = wv3 * 13;
        float acc[13];
        #pragma unroll
        for (int i = 0; i < 13; i++) acc[i] = 0.f;
        const float* xl = xbase + l * 192;
        const float* wb = xpw + (size_t)k * 38 * 192;
        for (int dd = 0; dd < 192; dd += 4) {
            float4 u4 = *(const float4*)(xl + dd);
            #pragma unroll
            for (int ci = 0; ci < 13; ci++) {
                int c = cbase + ci;
                if (c < 38) {
                    float4 w4 = *(const float4*)(wb + c * 192 + dd);  // s_load
                    acc[ci] = fmaf(u4.x, w4.x, acc[ci]);
                    acc[ci] = fmaf(u4.y, w4.y, acc[ci]);
                    acc[ci] = fmaf(u4.z, w4.z, acc[ci]);
                    acc[ci] = fmaf(u4.w, w4.w, acc[ci]);
                }
            }
        }
        #pragma unroll
        for (int ci = 0; ci < 13; ci++) {
            int c = cbase + ci;
            if (c < 38) {
                int slot = c + (c >= 6 ? 2 : 0);
                pT[g][l * 41 + slot] = acc[ci];
            }
        }
    }
    __syncthreads();
    float* pgout = Pg_all + (size_t)(chunk * 4 + k) * 2560;
    for (int i = tk; i < 2560; i += 192)
        pgout[i] = pT[g][(i / 40) * 41 + (i % 40)];    // coalesced
    __syncthreads();   // drain stores before uniform loads

    // scan: thread owns channel d = tk for direction k
    {
        int d = tk;
        int gd = k * 192 + d;
        float w6[6];
        #pragma unroll
        for (int r = 0; r < 6; r++) w6[r] = dtw[gd * 6 + r];
        float bias = dtb[gd];
        float a[16];
        #pragma unroll
        for (int n = 0; n < 16; n++) a[n] = -__expf(A_logs[gd * 16 + n]);
        bool pw = true;
        #pragma unroll
        for (int n = 1; n < 16; n++)
            pw = pw && (fabsf(a[n] - (float)(n + 1) * a[0]) <= 1e-4f * fabsf(a[n]) + 1e-6f);
        float hst[16];
        #pragma unroll
        for (int n = 0; n < 16; n++) hst[n] = 0.f;
        const float* pbase = Pg_all + (size_t)(chunk * 4 + k) * 2560;

        if (__all(pw)) {
            float a0 = a[0];
            float u_nxt = xbase[sperm(k, 0) * 192 + d];
            for (int l = 0; l < 64; l++) {
                int sl = sperm(k, l);
                float u = u_nxt;
                if (l < 63) u_nxt = xbase[sperm(k, l + 1) * 192 + d];
                const float* row = pbase + sl * PROW;  // uniform -> s_load
                float dp = bias;
                #pragma unroll
                for (int r = 0; r < 6; r++) dp = fmaf(row[r], w6[r], dp);
                float delta = (dp > 20.f) ? dp : __logf(1.f + __expf(dp));
                float du = delta * u;
                float e1 = __expf(delta * a0);
                float p[16];
                p[0] = e1;
                p[1] = e1 * e1;
                p[2] = p[1] * e1;   p[3] = p[1] * p[1];
                p[4] = p[3] * e1;   p[5] = p[3] * p[1];
                p[6] = p[3] * p[2]; p[7] = p[3] * p[3];
                p[8] = p[7] * e1;   p[9] = p[7] * p[1];
                p[10] = p[7] * p[2]; p[11] = p[7] * p[3];
                p[12] = p[7] * p[4]; p[13] = p[7] * p[5];
                p[14] = p[7] * p[6]; p[15] = p[7] * p[7];
                float y0 = 0.f, y1 = 0.f, y2 = 0.f, y3 = 0.f;
                #pragma unroll
                for (int n = 0; n < 16; n += 4) {
                    hst[n]     = fmaf(hst[n],     p[n],     du * row[8 + n]);
                    hst[n + 1] = fmaf(hst[n + 1], p[n + 1], du * row[9 + n]);
                    hst[n + 2] = fmaf(hst[n + 2], p[n + 2], du * row[10 + n]);
                    hst[n + 3] = fmaf(hst[n + 3], p[n + 3], du * row[11 + n]);
                    y0 = fmaf(hst[n],     row[24 + n], y0);
                    y1 = fmaf(hst[n + 1], row[25 + n], y1);
                    y2 = fmaf(hst[n + 2], row[26 + n], y2);
                    y3 = fmaf(hst[n + 3], row[27 + n], y3);
                }
                atomicAdd(&yac[sl * 192 + d], (y0 + y1) + (y2 + y3));
            }
        } else {
            for (int l = 0; l < 64; l++) {
                int sl = sperm(k, l);
                float u = xbase[sl * 192 + d];
                const float* row = pbase + sl * PROW;
                float dp = bias;
                #pragma unroll
                for (int r = 0; r < 6; r++) dp = fmaf(row[r], w6[r], dp);
                float delta = (dp > 20.f) ? dp : __logf(1.f + __expf(dp));
                float du = delta * u;
                float y = 0.f;
                #pragma unroll
                for (int n = 0; n < 16; n++) {
                    float e = __expf(delta * a[n]);
                    hst[n] = fmaf(hst[n], e, du * row[8 + n]);
                    y = fmaf(hst[n], row[24 + n], y);
                }
                atomicAdd(&yac[sl * 192 + d], y);
            }
        }
    }
    __syncthreads();

    if (pair == 0) {
        float* yo = yp0_all + (size_t)chunk * 12288;
        for (int i = t; i < 12288; i += 384) yo[i] = yac[i];
    } else {
        unsigned int* yo = yp1_b + (size_t)chunk * 6144;
        for (int i = t; i < 6144; i += 384)
            yo[i] = packbf(yac[2 * i], yac[2 * i + 1]);
    }
}

// ---- kE: y = yp0 + yp1; LN(192) + silu(z) gate -> g[dd][p]
__global__ __launch_bounds__(256) void kE(
        const float* __restrict__ yp0_all, const unsigned int* __restrict__ yp1_b,
        const unsigned int* __restrict__ zg_b,
        const float* __restrict__ og, const float* __restrict__ ob,
        float* __restrict__ g_all) {
    int blk = blockIdx.x;
    int xcd = blk & 7, j = blk >> 3;
    int chunk = xcd * 32 + (j >> 1), half = j & 1;
    int t = threadIdx.x;
    int p = half * 32 + (t >> 3), o = t & 7;
    int par = o & 1;
    const float* yrow = yp0_all + (size_t)chunk * 12288 + p * 192;
    const unsigned int* y1row = yp1_b + (size_t)chunk * 6144 + p * 96;
    float ys[24];
    float s = 0.f, sq = 0.f;
    #pragma unroll
    for (int jj = 0; jj < 24; jj++) {
        int i = o + 8 * jj;
        unsigned int w = y1row[i >> 1];
        float v = yrow[i] + bf2f(par ? (w >> 16) : (w & 0xFFFFu));
        ys[jj] = v; s += v; sq += v * v;
    }
    s += __shfl_xor(s, 1); sq += __shfl_xor(sq, 1);
    s += __shfl_xor(s, 2); sq += __shfl_xor(sq, 2);
    s += __shfl_xor(s, 4); sq += __shfl_xor(sq, 4);
    float m = s * (1.f / 192.f);
    float rinv = rsqrtf(sq * (1.f / 192.f) - m * m + 1e-5f);
    const unsigned int* z = zg_b + (size_t)chunk * 6144;
    float* g = g_all + (size_t)chunk * 12288;
    #pragma unroll
    for (int jj = 0; jj < 24; jj++) {
        int i = o + 8 * jj;
        float ln = (ys[jj] - m) * rinv * og[i] + ob[i];
        unsigned int zw = z[(i >> 1) * 64 + p];
        float zv = bf2f(par ? (zw >> 16) : (zw & 0xFFFFu));
        g[i * 64 + p] = ln * siluf_(zv);
    }
}

// ---- kF: out_proj GEMV 192->96 (cols cgf*24..+24) + residual recompute + blend
__global__ __launch_bounds__(256) void kF(
        const float* __restrict__ g_all, const float* __restrict__ Wout,  // (192,96)
        const float* __restrict__ x, const float* __restrict__ stats,
        const float* __restrict__ gamma, const float* __restrict__ beta,
        const float* __restrict__ alpha, float* __restrict__ out) {
    int blk = blockIdx.x;
    int xcd = blk & 7, j = blk >> 3;
    int chunk = xcd * 32 + (j >> 2), cgf = j & 3;
    int b = chunk >> 6, chh = (chunk >> 3) & 7, chw = chunk & 7;
    int t = threadIdx.x;
    int p = t & 63;
    int wv = __builtin_amdgcn_readfirstlane(t >> 6);   // 0..3
    int cbase = cgf * 24 + wv * 6;
    float acc[6];
    #pragma unroll
    for (int i = 0; i < 6; i++) acc[i] = 0.f;
    const float* g = g_all + (size_t)chunk * 12288;
    for (int dd = 0; dd < 192; dd++) {
        float u = g[dd * 64 + p];                      // coalesced
        const float* w = Wout + dd * 96 + cbase;       // uniform -> s_load
        #pragma unroll
        for (int i = 0; i < 6; i++) acc[i] = fmaf(u, w[i], acc[i]);
    }
    float al = alpha[0];
    int hh = chh * 8 + (p >> 3), ww = chw * 8 + (p & 7);
    #pragma unroll
    for (int i = 0; i < 6; i++) {
        int c = cbase + i;
        int bc = b * 96 + c;
        size_t gi = (((size_t)bc) * 64 + hh) * 64 + ww;
        float xv = x[gi];
        float xn = (xv - stats[bc]) * stats[384 + bc] * gamma[c] + beta[c];
        out[gi] = xv + al * (siluf_(xn) + acc[i]);
    }
}

extern "C" void kernel_launch(void* const* d_in, const int* in_sizes, int n_in,
                              void* d_out, int out_size, void* d_ws, size_t ws_size,
                              hipStream_t stream) {
    const float* x        = (const float*)d_in[0];
    const float* gamma    = (const float*)d_in[1];
    const float* beta     = (const float*)d_in[2];
    const float* alpha    = (const float*)d_in[3];
    const float* ln1_g    = (const float*)d_in[4];
    const float* ln1_b    = (const float*)d_in[5];
    const float* in_proj  = (const float*)d_in[6];
    const float* conv_w   = (const float*)d_in[7];
    const float* conv_b   = (const float*)d_in[8];
    const float* x_proj   = (const float*)d_in[9];
    const float* dt_w     = (const float*)d_in[10];
    const float* dt_b     = (const float*)d_in[11];
    const float* A_logs   = (const float*)d_in[12];
    const float* Ds       = (const float*)d_in[13];
    const float* onorm_g  = (const float*)d_in[14];
    const float* onorm_b  = (const float*)d_in[15];
    const float* out_proj = (const float*)d_in[16];
    float* out = (float*)d_out;

    float* ws    = (float*)d_ws;
    float* stats = ws;                            // 768 f
    float* xcg   = ws + 768;                      // 3,145,728 f ; yp0 alias after kB
    float* x0T   = xcg + 3145728;                 // 3,145,728 f ; g alias after kD
    float* Pg    = x0T + 3145728;                 // 2,621,440 f
    unsigned int* zg_b  = (unsigned int*)(Pg + 2621440);   // 1,572,864 u32
    unsigned int* yp1_b = zg_b + 1572864;         // 1,572,864 u32  (total ~48.2 MB)
    float* yp0   = xcg;                           // alias (xcg dead after kB)
    float* gbuf  = x0T;                           // alias (x0T dead after kD)

    hipLaunchKernelGGL(k1a_stats, dim3(384), dim3(256), 0, stream, x, stats);
    hipLaunchKernelGGL(kA, dim3(1024), dim3(256), 0, stream,
                       x, stats, gamma, beta, ln1_g, ln1_b, in_proj, xcg, zg_b);
    hipLaunchKernelGGL(kB, dim3(1024), dim3(256), 0, stream,
                       xcg, conv_w, conv_b, x0T);
    hipLaunchKernelGGL(kD, dim3(512), dim3(384), 0, stream,
                       x0T, x_proj, dt_w, dt_b, A_logs, Ds, Pg, yp0, yp1_b);
    hipLaunchKernelGGL(kE, dim3(512), dim3(256), 0, stream,
                       yp0, yp1_b, zg_b, onorm_g, onorm_b, gbuf);
    hipLaunchKernelGGL(kF, dim3(1024), dim3(256), 0, stream,
                       gbuf, out_proj, x, stats, gamma, beta, alpha, out);
}

// Round 8
// 207.998 us; speedup vs baseline: 1.2812x; 1.2812x over previous
//
#include <hip/hip_runtime.h>
#include <math.h>

__device__ __forceinline__ float siluf_(float x) {
    return x / (1.f + __expf(-x));
}

// Direction permutation (involution): xs[k][d][l] = x0[d][sperm(k,l)]
__device__ __forceinline__ int sperm(int k, int l) {
    int t = (k & 1) ? (((l & 7) << 3) | (l >> 3)) : l;
    return (k & 2) ? (63 - t) : t;
}

// bf16 pack/unpack (RNE)
__device__ __forceinline__ unsigned int f2bf(float f) {
    unsigned int u = __float_as_uint(f);
    return (u + 0x7FFFu + ((u >> 16) & 1u)) >> 16;
}
__device__ __forceinline__ float bf2f(unsigned int h) {
    return __uint_as_float(h << 16);
}
__device__ __forceinline__ unsigned int packbf(float lo, float hi) {
    return f2bf(lo) | (f2bf(hi) << 16);
}

// ---------------------------------------------------------------- k1a: stats
__global__ void k1a_stats(const float* __restrict__ x, float* __restrict__ stats) {
    int bc = blockIdx.x;                 // b*96 + c
    const float* xp = x + (size_t)bc * 4096;
    float s = 0.f, sq = 0.f;
    for (int i = threadIdx.x; i < 4096; i += 256) {
        float v = xp[i]; s += v; sq += v * v;
    }
    __shared__ float rs[256], rq[256];
    rs[threadIdx.x] = s; rq[threadIdx.x] = sq;
    __syncthreads();
    for (int off = 128; off > 0; off >>= 1) {
        if (threadIdx.x < off) {
            rs[threadIdx.x] += rs[threadIdx.x + off];
            rq[threadIdx.x] += rq[threadIdx.x + off];
        }
        __syncthreads();
    }
    if (threadIdx.x == 0) {
        float m = rs[0] * (1.f / 4096.f);
        float v = rq[0] * (1.f / 4096.f) - m * m;
        stats[bc] = m;
        stats[384 + bc] = rsqrtf(v + 1e-5f);
    }
}

// ---- kA: spatial-norm+SiLU + LN(96) + in_proj cols [cg*96, cg*96+96)
__global__ __launch_bounds__(256) void kA(
        const float* __restrict__ x, const float* __restrict__ stats,
        const float* __restrict__ gamma, const float* __restrict__ beta,
        const float* __restrict__ ln1_g, const float* __restrict__ ln1_b,
        const float* __restrict__ Win,       // (96,384)
        float* __restrict__ xcg_all,         // [chunk][192][64] f32
        unsigned int* __restrict__ zg_b) {   // [chunk][96][64] packed bf16x2
    int blk = blockIdx.x;
    int xcd = blk & 7, j = blk >> 3;
    int chunk = xcd * 32 + (j >> 2), cg = j & 3;
    int b = chunk >> 6, chh = (chunk >> 3) & 7, chw = chunk & 7;
    __shared__ float hs[64 * 97];
    int t = threadIdx.x;
    for (int i = t; i < 6144; i += 256) {
        int c = i >> 6, pos = i & 63;
        int bc = b * 96 + c;
        int hh = chh * 8 + (pos >> 3), ww = chw * 8 + (pos & 7);
        float v = x[(((size_t)bc) * 64 + hh) * 64 + ww];
        float xn = (v - stats[bc]) * stats[384 + bc] * gamma[c] + beta[c];
        hs[pos * 97 + c] = siluf_(xn);
    }
    __syncthreads();
    {   // LN over 96: 4 lanes per position
        int p = t >> 2, o = t & 3;
        float s = 0.f, sq = 0.f;
        #pragma unroll
        for (int jj = 0; jj < 24; jj++) { float v = hs[p * 97 + o + 4 * jj]; s += v; sq += v * v; }
        s += __shfl_xor(s, 1); sq += __shfl_xor(sq, 1);
        s += __shfl_xor(s, 2); sq += __shfl_xor(sq, 2);
        float m = s * (1.f / 96.f);
        float rinv = rsqrtf(sq * (1.f / 96.f) - m * m + 1e-5f);
        #pragma unroll
        for (int jj = 0; jj < 24; jj++) {
            int c = o + 4 * jj;
            hs[p * 97 + c] = (hs[p * 97 + c] - m) * rinv * ln1_g[c] + ln1_b[c];
        }
    }
    __syncthreads();
    int p = t & 63;
    int wv = __builtin_amdgcn_readfirstlane(t >> 6);   // 0..3
    int jbase = cg * 96 + wv * 24;
    float acc[24];
    #pragma unroll
    for (int i = 0; i < 24; i++) acc[i] = 0.f;
    for (int c = 0; c < 96; c++) {
        float u = hs[p * 97 + c];
        const float* w = Win + c * 384 + jbase;        // wave-uniform -> s_load
        #pragma unroll
        for (int i = 0; i < 24; i++) acc[i] = fmaf(u, w[i], acc[i]);
    }
    if (jbase < 192) {
        float* o_ = xcg_all + (size_t)chunk * 12288 + jbase * 64 + p;
        #pragma unroll
        for (int i = 0; i < 24; i++) o_[i * 64] = acc[i];
    } else {
        int i2base = (jbase - 192) >> 1;
        unsigned int* o_ = zg_b + (size_t)chunk * 6144 + i2base * 64 + p;
        #pragma unroll
        for (int i = 0; i < 12; i++) o_[i * 64] = packbf(acc[2 * i], acc[2 * i + 1]);
    }
}

// ---- kB: depthwise 3x3 + bias + SiLU; channels [dg*48, +48) -> x0T[l][192]
__global__ __launch_bounds__(256) void kB(
        const float* __restrict__ xcg_all, const float* __restrict__ conv_w,
        const float* __restrict__ conv_b, float* __restrict__ x0T_all) {
    int blk = blockIdx.x;
    int xcd = blk & 7, j = blk >> 3;
    int chunk = xcd * 32 + (j >> 2), dg = j & 3;
    int dbase = dg * 48;
    __shared__ float tile[48 * 65];
    int t = threadIdx.x;
    const float* in = xcg_all + (size_t)chunk * 12288 + dbase * 64;
    for (int i = t; i < 3072; i += 256) tile[(i >> 6) * 65 + (i & 63)] = in[i];
    __syncthreads();
    float* o = x0T_all + (size_t)chunk * 12288;
    for (int s = 0; s < 12; s++) {
        int idx = s * 256 + t;                 // < 3072
        int l = idx / 48, dl = idx - l * 48;
        int r = l >> 3, cc = l & 7;
        int d = dbase + dl;
        float acc = conv_b[d];
        #pragma unroll
        for (int dh = 0; dh < 3; dh++) {
            int rr = r + dh - 1;
            if (rr < 0 || rr > 7) continue;
            #pragma unroll
            for (int dw = 0; dw < 3; dw++) {
                int cw = cc + dw - 1;
                if (cw < 0 || cw > 7) continue;
                acc = fmaf(tile[dl * 65 + rr * 8 + cw], conv_w[d * 9 + dh * 3 + dw], acc);
            }
        }
        o[l * 192 + d] = siluf_(acc);
    }
}

// ---- kD: block = (chunk, k), 192 threads, XCD-swizzled so a chunk's 4 blocks
// share one XCD L2. proj -> pT in LDS (slot rows, 160B); scan reads rows as
// wave-uniform ds_read_b128 broadcasts; merge via global f32 atomics (local L2).
__global__ __launch_bounds__(192) void kD(
        const float* __restrict__ x0T_all, const float* __restrict__ xpw, // (4,38,192)
        const float* __restrict__ dtw, const float* __restrict__ dtb,
        const float* __restrict__ A_logs, const float* __restrict__ Ds,
        float* __restrict__ yac_all) {       // [chunk][64][192] f32, pre-zeroed
    int blk = blockIdx.x;
    int xcd = blk & 7, j = blk >> 3;         // j: 0..127
    int chunk = xcd * 32 + (j >> 2);
    int k = j & 3;
    __shared__ float pT[64 * 40];            // [l][slot]: 0-5 dts, 8-23 B, 24-39 C
    int t = threadIdx.x;
    const float* xbase = x0T_all + (size_t)chunk * 12288;

    // proj: P[c][l] = sum_dd xpw[k][c][dd] * x0T[l][dd]
    {
        int l = t & 63;
        int wv3 = __builtin_amdgcn_readfirstlane(t >> 6);  // 0..2
        int cbase = wv3 * 13;
        float acc[13];
        #pragma unroll
        for (int i = 0; i < 13; i++) acc[i] = 0.f;
        const float* xl = xbase + l * 192;
        const float* wb = xpw + (size_t)k * 38 * 192;
        for (int dd = 0; dd < 192; dd += 4) {
            float4 u4 = *(const float4*)(xl + dd);         // per-lane, coalesced
            #pragma unroll
            for (int ci = 0; ci < 13; ci++) {
                int c = cbase + ci;
                if (c < 38) {
                    float4 w4 = *(const float4*)(wb + c * 192 + dd);  // s_load
                    acc[ci] = fmaf(u4.x, w4.x, acc[ci]);
                    acc[ci] = fmaf(u4.y, w4.y, acc[ci]);
                    acc[ci] = fmaf(u4.z, w4.z, acc[ci]);
                    acc[ci] = fmaf(u4.w, w4.w, acc[ci]);
                }
            }
        }
        #pragma unroll
        for (int ci = 0; ci < 13; ci++) {
            int c = cbase + ci;
            if (c < 38) {
                int slot = c + (c >= 6 ? 2 : 0);
                pT[l * 40 + slot] = acc[ci];
            }
        }
    }
    __syncthreads();

    // scan: thread owns channel d for direction k
    {
        int d = t;                                         // 0..191
        int gd = k * 192 + d;
        float w6[6];
        #pragma unroll
        for (int r = 0; r < 6; r++) w6[r] = dtw[gd * 6 + r];
        float bias = dtb[gd];
        float Dd = Ds[gd];
        float a[16];
        #pragma unroll
        for (int n = 0; n < 16; n++) a[n] = -__expf(A_logs[gd * 16 + n]);
        bool pw = true;
        #pragma unroll
        for (int n = 1; n < 16; n++)
            pw = pw && (fabsf(a[n] - (float)(n + 1) * a[0]) <= 1e-4f * fabsf(a[n]) + 1e-6f);
        float hst[16];
        #pragma unroll
        for (int n = 0; n < 16; n++) hst[n] = 0.f;
        float* yo = yac_all + (size_t)chunk * 12288;

        if (__all(pw)) {
            float a0 = a[0];
            float u_nxt = xbase[sperm(k, 0) * 192 + d];
            for (int l = 0; l < 64; l++) {
                int sl = sperm(k, l);
                const float4* r4 = (const float4*)(pT + sl * 40);  // uniform bcast
                float4 rA = r4[0], rB = r4[1];
                float4 b0 = r4[2], b1 = r4[3], b2 = r4[4], b3 = r4[5];
                float4 c0 = r4[6], c1 = r4[7], c2 = r4[8], c3 = r4[9];
                float u = u_nxt;
                if (l < 63) u_nxt = xbase[sperm(k, l + 1) * 192 + d];  // prefetch
                float dp = bias;
                dp = fmaf(rA.x, w6[0], dp); dp = fmaf(rA.y, w6[1], dp);
                dp = fmaf(rA.z, w6[2], dp); dp = fmaf(rA.w, w6[3], dp);
                dp = fmaf(rB.x, w6[4], dp); dp = fmaf(rB.y, w6[5], dp);
                float delta = (dp > 20.f) ? dp : __logf(1.f + __expf(dp));
                float du = delta * u;
                float e1 = __expf(delta * a0);
                float p[16];
                p[0] = e1;
                p[1] = e1 * e1;
                p[2] = p[1] * e1;   p[3] = p[1] * p[1];
                p[4] = p[3] * e1;   p[5] = p[3] * p[1];
                p[6] = p[3] * p[2]; p[7] = p[3] * p[3];
                p[8] = p[7] * e1;   p[9] = p[7] * p[1];
                p[10] = p[7] * p[2]; p[11] = p[7] * p[3];
                p[12] = p[7] * p[4]; p[13] = p[7] * p[5];
                p[14] = p[7] * p[6]; p[15] = p[7] * p[7];
                float y0 = 0.f, y1 = 0.f, y2 = 0.f, y3 = 0.f;
                hst[0]  = fmaf(hst[0],  p[0],  du * b0.x); y0 = fmaf(hst[0],  c0.x, y0);
                hst[1]  = fmaf(hst[1],  p[1],  du * b0.y); y1 = fmaf(hst[1],  c0.y, y1);
                hst[2]  = fmaf(hst[2],  p[2],  du * b0.z); y2 = fmaf(hst[2],  c0.z, y2);
                hst[3]  = fmaf(hst[3],  p[3],  du * b0.w); y3 = fmaf(hst[3],  c0.w, y3);
                hst[4]  = fmaf(hst[4],  p[4],  du * b1.x); y0 = fmaf(hst[4],  c1.x, y0);
                hst[5]  = fmaf(hst[5],  p[5],  du * b1.y); y1 = fmaf(hst[5],  c1.y, y1);
                hst[6]  = fmaf(hst[6],  p[6],  du * b1.z); y2 = fmaf(hst[6],  c1.z, y2);
                hst[7]  = fmaf(hst[7],  p[7],  du * b1.w); y3 = fmaf(hst[7],  c1.w, y3);
                hst[8]  = fmaf(hst[8],  p[8],  du * b2.x); y0 = fmaf(hst[8],  c2.x, y0);
                hst[9]  = fmaf(hst[9],  p[9],  du * b2.y); y1 = fmaf(hst[9],  c2.y, y1);
                hst[10] = fmaf(hst[10], p[10], du * b2.z); y2 = fmaf(hst[10], c2.z, y2);
                hst[11] = fmaf(hst[11], p[11], du * b2.w); y3 = fmaf(hst[11], c2.w, y3);
                hst[12] = fmaf(hst[12], p[12], du * b3.x); y0 = fmaf(hst[12], c3.x, y0);
                hst[13] = fmaf(hst[13], p[13], du * b3.y); y1 = fmaf(hst[13], c3.y, y1);
                hst[14] = fmaf(hst[14], p[14], du * b3.z); y2 = fmaf(hst[14], c3.z, y2);
                hst[15] = fmaf(hst[15], p[15], du * b3.w); y3 = fmaf(hst[15], c3.w, y3);
                atomicAdd(&yo[sl * 192 + d], (y0 + y1) + (y2 + y3) + Dd * u);
            }
        } else {
            for (int l = 0; l < 64; l++) {
                int sl = sperm(k, l);
                float u = xbase[sl * 192 + d];
                const float* row = pT + sl * 40;
                float dp = bias;
                #pragma unroll
                for (int r = 0; r < 6; r++) dp = fmaf(row[r + (r >= 6 ? 2 : 0)], w6[r], dp);
                float delta = (dp > 20.f) ? dp : __logf(1.f + __expf(dp));
                float du = delta * u;
                float y = 0.f;
                #pragma unroll
                for (int n = 0; n < 16; n++) {
                    float e = __expf(delta * a[n]);
                    hst[n] = fmaf(hst[n], e, du * row[8 + n]);
                    y = fmaf(hst[n], row[24 + n], y);
                }
                atomicAdd(&yo[sl * 192 + d], y + Dd * u);
            }
        }
    }
}

// ---- kE: LN(192) over y + silu(z) gate -> g[dd][p]
__global__ __launch_bounds__(256) void kE(
        const float* __restrict__ yac_all, const unsigned int* __restrict__ zg_b,
        const float* __restrict__ og, const float* __restrict__ ob,
        float* __restrict__ g_all) {
    int blk = blockIdx.x;
    int xcd = blk & 7, j = blk >> 3;
    int chunk = xcd * 32 + (j >> 1), half = j & 1;
    int t = threadIdx.x;
    int p = half * 32 + (t >> 3), o = t & 7;
    int par = o & 1;
    const float* yrow = yac_all + (size_t)chunk * 12288 + p * 192;
    float ys[24];
    float s = 0.f, sq = 0.f;
    #pragma unroll
    for (int jj = 0; jj < 24; jj++) {
        float v = yrow[o + 8 * jj];
        ys[jj] = v; s += v; sq += v * v;
    }
    s += __shfl_xor(s, 1); sq += __shfl_xor(sq, 1);
    s += __shfl_xor(s, 2); sq += __shfl_xor(sq, 2);
    s += __shfl_xor(s, 4); sq += __shfl_xor(sq, 4);
    float m = s * (1.f / 192.f);
    float rinv = rsqrtf(sq * (1.f / 192.f) - m * m + 1e-5f);
    const unsigned int* z = zg_b + (size_t)chunk * 6144;
    float* g = g_all + (size_t)chunk * 12288;
    #pragma unroll
    for (int jj = 0; jj < 24; jj++) {
        int i = o + 8 * jj;
        float ln = (ys[jj] - m) * rinv * og[i] + ob[i];
        unsigned int zw = z[(i >> 1) * 64 + p];
        float zv = bf2f(par ? (zw >> 16) : (zw & 0xFFFFu));
        g[i * 64 + p] = ln * siluf_(zv);
    }
}

// ---- kF: out_proj GEMV 192->96 (cols cgf*24..+24) + residual recompute + blend
__global__ __launch_bounds__(256) void kF(
        const float* __restrict__ g_all, const float* __restrict__ Wout,  // (192,96)
        const float* __restrict__ x, const float* __restrict__ stats,
        const float* __restrict__ gamma, const float* __restrict__ beta,
        const float* __restrict__ alpha, float* __restrict__ out) {
    int blk = blockIdx.x;
    int xcd = blk & 7, j = blk >> 3;
    int chunk = xcd * 32 + (j >> 2), cgf = j & 3;
    int b = chunk >> 6, chh = (chunk >> 3) & 7, chw = chunk & 7;
    int t = threadIdx.x;
    int p = t & 63;
    int wv = __builtin_amdgcn_readfirstlane(t >> 6);   // 0..3
    int cbase = cgf * 24 + wv * 6;
    float acc[6];
    #pragma unroll
    for (int i = 0; i < 6; i++) acc[i] = 0.f;
    const float* g = g_all + (size_t)chunk * 12288;
    for (int dd = 0; dd < 192; dd++) {
        float u = g[dd * 64 + p];                      // coalesced
        const float* w = Wout + dd * 96 + cbase;       // uniform -> s_load
        #pragma unroll
        for (int i = 0; i < 6; i++) acc[i] = fmaf(u, w[i], acc[i]);
    }
    float al = alpha[0];
    int hh = chh * 8 + (p >> 3), ww = chw * 8 + (p & 7);
    #pragma unroll
    for (int i = 0; i < 6; i++) {
        int c = cbase + i;
        int bc = b * 96 + c;
        size_t gi = (((size_t)bc) * 64 + hh) * 64 + ww;
        float xv = x[gi];
        float xn = (xv - stats[bc]) * stats[384 + bc] * gamma[c] + beta[c];
        out[gi] = xv + al * (siluf_(xn) + acc[i]);
    }
}

extern "C" void kernel_launch(void* const* d_in, const int* in_sizes, int n_in,
                              void* d_out, int out_size, void* d_ws, size_t ws_size,
                              hipStream_t stream) {
    const float* x        = (const float*)d_in[0];
    const float* gamma    = (const float*)d_in[1];
    const float* beta     = (const float*)d_in[2];
    const float* alpha    = (const float*)d_in[3];
    const float* ln1_g    = (const float*)d_in[4];
    const float* ln1_b    = (const float*)d_in[5];
    const float* in_proj  = (const float*)d_in[6];
    const float* conv_w   = (const float*)d_in[7];
    const float* conv_b   = (const float*)d_in[8];
    const float* x_proj   = (const float*)d_in[9];
    const float* dt_w     = (const float*)d_in[10];
    const float* dt_b     = (const float*)d_in[11];
    const float* A_logs   = (const float*)d_in[12];
    const float* Ds       = (const float*)d_in[13];
    const float* onorm_g  = (const float*)d_in[14];
    const float* onorm_b  = (const float*)d_in[15];
    const float* out_proj = (const float*)d_in[16];
    float* out = (float*)d_out;

    float* ws    = (float*)d_ws;
    float* stats = ws;                            // 768 f
    float* xcg   = ws + 768;                      // 3,145,728 f ; yac alias after kB
    float* x0T   = xcg + 3145728;                 // 3,145,728 f ; g alias after kD
    unsigned int* zg_b = (unsigned int*)(x0T + 3145728);   // 1,572,864 u32 (~31.5 MB total)
    float* yac   = xcg;                           // alias (xcg dead after kB)
    float* gbuf  = x0T;                           // alias (x0T dead after kD)

    hipLaunchKernelGGL(k1a_stats, dim3(384), dim3(256), 0, stream, x, stats);
    hipLaunchKernelGGL(kA, dim3(1024), dim3(256), 0, stream,
                       x, stats, gamma, beta, ln1_g, ln1_b, in_proj, xcg, zg_b);
    hipLaunchKernelGGL(kB, dim3(1024), dim3(256), 0, stream,
                       xcg, conv_w, conv_b, x0T);
    hipMemsetAsync(yac, 0, (size_t)3145728 * 4, stream);   // yac = 0 (aliases xcg)
    hipLaunchKernelGGL(kD, dim3(1024), dim3(192), 0, stream,
                       x0T, x_proj, dt_w, dt_b, A_logs, Ds, yac);
    hipLaunchKernelGGL(kE, dim3(512), dim3(256), 0, stream,
                       yac, zg_b, onorm_g, onorm_b, gbuf);
    hipLaunchKernelGGL(kF, dim3(1024), dim3(256), 0, stream,
                       gbuf, out_proj, x, stats, gamma, beta, alpha, out);
}